// Round 6
// baseline (790.188 us; speedup 1.0000x reference)
//
#include <hip/hip_runtime.h>
#include <math.h>

#define N 8192
#define IN_DIM 128
#define HID 32

#define RB 128          // rows per spmm block
#define KT 64           // k-tile
#define NT (KCHUNK / KT)
#define SK 16           // split-K factor
#define KCHUNK (N / SK) // 512

__device__ __forceinline__ void fma4(float4& acc, float a, const float4& b) {
    acc.x = fmaf(a, b.x, acc.x);
    acc.y = fmaf(a, b.y, acc.y);
    acc.z = fmaf(a, b.z, acc.z);
    acc.w = fmaf(a, b.w, acc.w);
}

// Fused: degree + z1.  Block owns 8 rows.
//   dinv[i] = 1/sqrt(max(1 + sum_j adj[i][j], 1))   (32 lanes per row, shfl reduce)
//   Zs[i][c] = dinv[i] * (x[i] @ W1 + b1)[c]
__global__ __launch_bounds__(256) void k_deg_z1(const float* __restrict__ adj,
                                                const float* __restrict__ x,
                                                const float* __restrict__ W1,
                                                const float* __restrict__ b1,
                                                float* __restrict__ dinv,
                                                float* __restrict__ Zs) {
    __shared__ float Ws[IN_DIM * HID];  // 4096 floats
    __shared__ float xs[8 * IN_DIM];    // 1024 floats
    int t = threadIdx.x;
    int row0 = blockIdx.x * 8;
    int g = t >> 5, c = t & 31;
#pragma unroll
    for (int i = 0; i < 4; ++i)
        *(float4*)&Ws[(i * 256 + t) * 4] = *(const float4*)&W1[(i * 256 + t) * 4];
    *(float4*)&xs[t * 4] = *(const float4*)&x[(size_t)row0 * IN_DIM + t * 4];

    // degree for row (row0+g): 32 lanes, coalesced 512B segments per step
    int row = row0 + g;
    const float4* rp = (const float4*)(adj + (size_t)row * N);
    float s = 0.f;
#pragma unroll 8
    for (int i = 0; i < 64; ++i) {
        float4 v = rp[c + i * 32];
        s += v.x + v.y + v.z + v.w;
    }
#pragma unroll
    for (int off = 16; off > 0; off >>= 1) s += __shfl_xor(s, off, 64);
    float deg = fmaxf(s + 1.0f, 1.0f);  // +1 self loop
    float di = 1.0f / sqrtf(deg);
    if (c == 0) dinv[row] = di;

    __syncthreads();
    float acc = b1[c];
#pragma unroll 8
    for (int k = 0; k < IN_DIM; ++k) acc = fmaf(xs[g * IN_DIM + k], Ws[k * HID + c], acc);
    Zs[(size_t)row * HID + c] = di * acc;
}

// P[sk] = adj[rows, kchunk_sk] @ Zs[kchunk_sk, 32]
// Round-2 swizzled tile (A-reads conflict-free) + 2-phase reg-staged pipeline:
//   issue tile t+1's global loads after barrier 1, compute tile t, ds_write after
//   barrier 2 -> HBM latency hides under compute (T14 / minimum 2-phase).
// As swizzle: float4 slot fi of row stored at fi ^ ((row>>1)&7); reads use the
// same XOR -> 2 rows per 4-bank group = conflict-free (m136: 2-way is free).
__global__ __launch_bounds__(256, 4) void k_spmm(const float* __restrict__ adj,
                                                 const float* __restrict__ Zs,
                                                 float* __restrict__ P) {
    __shared__ float As[RB * KT];   // 32 KB, swizzled
    __shared__ float Bs[KT * HID];  // 8 KB
    int t = threadIdx.x;
    int r0 = blockIdx.x * RB;
    int k0 = blockIdx.y * KCHUNK;
    int cg = t & 3;           // 4 col groups of 8
    int rp2 = (t >> 2) * 2;   // row pair base 0..126
    int e = (rp2 >> 1) & 7;   // swizzle key (same for rp2 and rp2+1)
    float4 acc00 = {0, 0, 0, 0}, acc01 = {0, 0, 0, 0};
    float4 acc10 = {0, 0, 0, 0}, acc11 = {0, 0, 0, 0};

    // precomputed per-thread staging geometry
    int srow[8], sfi[8];
#pragma unroll
    for (int i = 0; i < 8; ++i) {
        int f = i * 256 + t;
        srow[i] = f >> 4;                       // 16 float4 per row
        sfi[i] = (f & 15) ^ ((srow[i] >> 1) & 7);
    }

    float4 ar[8], br[2];
    // prologue: issue tile-0 loads
#pragma unroll
    for (int i = 0; i < 8; ++i) {
        int f = i * 256 + t;
        ar[i] = *(const float4*)&adj[(size_t)(r0 + (f >> 4)) * N + k0 + (f & 15) * 4];
    }
#pragma unroll
    for (int i = 0; i < 2; ++i)
        br[i] = ((const float4*)(Zs + (size_t)k0 * HID))[i * 256 + t];

    for (int tile = 0; tile < NT; ++tile) {
        // write staged regs to LDS (vmcnt wait lands here, after prior compute)
#pragma unroll
        for (int i = 0; i < 8; ++i)
            *(float4*)&As[srow[i] * KT + sfi[i] * 4] = ar[i];
#pragma unroll
        for (int i = 0; i < 2; ++i)
            ((float4*)Bs)[i * 256 + t] = br[i];
        __syncthreads();

        // issue next tile's global loads (in flight during compute)
        if (tile + 1 < NT) {
            int ktn = k0 + (tile + 1) * KT;
#pragma unroll
            for (int i = 0; i < 8; ++i) {
                int f = i * 256 + t;
                ar[i] = *(const float4*)&adj[(size_t)(r0 + (f >> 4)) * N + ktn + (f & 15) * 4];
            }
#pragma unroll
            for (int i = 0; i < 2; ++i)
                br[i] = ((const float4*)(Zs + (size_t)ktn * HID))[i * 256 + t];
        }

        // compute on LDS
#pragma unroll
        for (int kk = 0; kk < KT; kk += 4) {
            int s0 = ((kk >> 2) ^ e) * 4;  // swizzled read slot for this row pair
            float a0[4], a1[4];
            *(float4*)a0 = *(const float4*)&As[rp2 * KT + s0];
            *(float4*)a1 = *(const float4*)&As[(rp2 + 1) * KT + s0];
#pragma unroll
            for (int j = 0; j < 4; ++j) {
                float4 z0 = *(const float4*)&Bs[(kk + j) * HID + cg * 8];
                float4 z1 = *(const float4*)&Bs[(kk + j) * HID + cg * 8 + 4];
                fma4(acc00, a0[j], z0);
                fma4(acc01, a0[j], z1);
                fma4(acc10, a1[j], z0);
                fma4(acc11, a1[j], z1);
            }
        }
        __syncthreads();
    }

    float* p0 = P + (size_t)blockIdx.y * (N * HID) + (size_t)(r0 + rp2) * HID + cg * 8;
    float* p1 = p0 + HID;
    *(float4*)(p0)     = acc00;
    *(float4*)(p0 + 4) = acc01;
    *(float4*)(p1)     = acc10;
    *(float4*)(p1 + 4) = acc11;
}

// H = relu(dinv * (sum_sk P[sk] + Zs)); then Zout = dinv * (H @ W2 + b2)   (fused fin+z2)
__global__ __launch_bounds__(256) void k_fin_z2(const float* __restrict__ P,
                                                const float* __restrict__ Zin,
                                                const float* __restrict__ dinv,
                                                const float* __restrict__ W2,
                                                const float* __restrict__ b2,
                                                float* __restrict__ Zout) {
    __shared__ float Ws[HID * HID];  // 1024 floats
    __shared__ float hs[8][HID];
    int t = threadIdx.x;
    int row0 = blockIdx.x * 8;
    *(float4*)&Ws[t * 4] = *(const float4*)&W2[t * 4];
    int r = t >> 5, c = t & 31;
    size_t idx = (size_t)row0 * HID + t;   // 256 consecutive elements
    float v = Zin[idx];
#pragma unroll
    for (int s = 0; s < SK; ++s) v += P[(size_t)s * (N * HID) + idx];
    int row = row0 + r;
    hs[r][c] = fmaxf(dinv[row] * v, 0.f);
    __syncthreads();
    float acc = b2[c];
#pragma unroll
    for (int k = 0; k < HID; ++k) acc = fmaf(hs[r][k], Ws[k * HID + c], acc);
    Zout[idx] = dinv[row] * acc;
}

// H = relu(dinv * (sum_sk P[sk] + Zs)); out[i] = H[i] @ W3 + b3   (fused fin+out)
__global__ __launch_bounds__(256) void k_fin_out(const float* __restrict__ P,
                                                 const float* __restrict__ Zin,
                                                 const float* __restrict__ dinv,
                                                 const float* __restrict__ W3,
                                                 const float* __restrict__ b3,
                                                 float* __restrict__ out) {
    int t = threadIdx.x;
    size_t idx = (size_t)blockIdx.x * 256 + t;
    int row = (int)(idx >> 5);
    int c = t & 31;
    float v = Zin[idx];
#pragma unroll
    for (int s = 0; s < SK; ++s) v += P[(size_t)s * (N * HID) + idx];
    float h = fmaxf(dinv[row] * v, 0.f);
    float hw = h * W3[c];
#pragma unroll
    for (int off = 16; off > 0; off >>= 1) hw += __shfl_xor(hw, off, 32);
    if (c == 0) out[row] = hw + b3[0];
}

extern "C" void kernel_launch(void* const* d_in, const int* in_sizes, int n_in,
                              void* d_out, int out_size, void* d_ws, size_t ws_size,
                              hipStream_t stream) {
    const float* x   = (const float*)d_in[0];
    const float* adj = (const float*)d_in[1];
    const float* W1  = (const float*)d_in[2];
    const float* b1  = (const float*)d_in[3];
    const float* W2  = (const float*)d_in[4];
    const float* b2  = (const float*)d_in[5];
    const float* W3  = (const float*)d_in[6];
    const float* b3  = (const float*)d_in[7];
    float* out = (float*)d_out;

    float* dinv = (float*)d_ws;               // N floats
    float* Zs1  = dinv + N;                   // N*32 floats (1 MB)
    float* Zs2  = Zs1 + (size_t)N * HID;      // N*32 floats (1 MB)
    float* P    = Zs2 + (size_t)N * HID;      // SK*N*32 floats (16 MB)

    k_deg_z1<<<N / 8, 256, 0, stream>>>(adj, x, W1, b1, dinv, Zs1);

    k_spmm<<<dim3(N / RB, SK), 256, 0, stream>>>(adj, Zs1, P);
    k_fin_z2<<<N / 8, 256, 0, stream>>>(P, Zs1, dinv, W2, b2, Zs2);

    k_spmm<<<dim3(N / RB, SK), 256, 0, stream>>>(adj, Zs2, P);
    k_fin_out<<<N * HID / 256, 256, 0, stream>>>(P, Zs2, dinv, W3, b3, out);
}

// Round 7
// 522.705 us; speedup vs baseline: 1.5117x; 1.5117x over previous
//
#include <hip/hip_runtime.h>
#include <math.h>

#define N 8192
#define IN_DIM 128
#define HID 32

#define RB 128          // rows per spmm block
#define KT 32           // k-tile (small: double-buffer fits 40KB -> 4 blocks/CU)
#define SK 16           // split-K factor
#define KCHUNK (N / SK) // 512
#define NT (KCHUNK / KT) // 16

__device__ __forceinline__ void fma4(float4& acc, float a, const float4& b) {
    acc.x = fmaf(a, b.x, acc.x);
    acc.y = fmaf(a, b.y, acc.y);
    acc.z = fmaf(a, b.z, acc.z);
    acc.w = fmaf(a, b.w, acc.w);
}

// async global->LDS, 16B per lane, no VGPR round-trip (nothing to spill)
__device__ __forceinline__ void gload16(const float* g, float* l) {
    __builtin_amdgcn_global_load_lds(
        (const __attribute__((address_space(1))) void*)g,
        (__attribute__((address_space(3))) void*)l, 16, 0, 0);
}

// Fused: degree + z1.  Block owns 8 rows.
__global__ __launch_bounds__(256) void k_deg_z1(const float* __restrict__ adj,
                                                const float* __restrict__ x,
                                                const float* __restrict__ W1,
                                                const float* __restrict__ b1,
                                                float* __restrict__ dinv,
                                                float* __restrict__ Zs) {
    __shared__ float Ws[IN_DIM * HID];  // 4096 floats
    __shared__ float xs[8 * IN_DIM];    // 1024 floats
    int t = threadIdx.x;
    int row0 = blockIdx.x * 8;
    int g = t >> 5, c = t & 31;
#pragma unroll
    for (int i = 0; i < 4; ++i)
        *(float4*)&Ws[(i * 256 + t) * 4] = *(const float4*)&W1[(i * 256 + t) * 4];
    *(float4*)&xs[t * 4] = *(const float4*)&x[(size_t)row0 * IN_DIM + t * 4];

    int row = row0 + g;
    const float4* rp = (const float4*)(adj + (size_t)row * N);
    float s = 0.f;
#pragma unroll 8
    for (int i = 0; i < 64; ++i) {
        float4 v = rp[c + i * 32];
        s += v.x + v.y + v.z + v.w;
    }
#pragma unroll
    for (int off = 16; off > 0; off >>= 1) s += __shfl_xor(s, off, 64);
    float deg = fmaxf(s + 1.0f, 1.0f);  // +1 self loop
    float di = 1.0f / sqrtf(deg);
    if (c == 0) dinv[row] = di;

    __syncthreads();
    float acc = b1[c];
#pragma unroll 8
    for (int k = 0; k < IN_DIM; ++k) acc = fmaf(xs[g * IN_DIM + k], Ws[k * HID + c], acc);
    Zs[(size_t)row * HID + c] = di * acc;
}

// P[sk] = adj[rows, kchunk_sk] @ Zs[kchunk_sk, 32]
// T3 minimum 2-phase: global_load_lds double-buffer; loads for tile t+1 stay
// in flight across tile t's compute; one vmcnt-drain+barrier per tile.
// LDS is written LINEARLY by gload_lds (rule #21); the XOR swizzle is applied
// on the GLOBAL source address: LDS slot (row,p) holds global float4
// (row, p ^ ((row>>1)&7)). Reads use the same involution -> slots spread over
// all 8 bank-quads, 8 rows/quad balanced = conflict-free (PMC-verified r6: 0).
__global__ __launch_bounds__(256) void k_spmm(const float* __restrict__ adj,
                                              const float* __restrict__ Zs,
                                              float* __restrict__ P) {
    __shared__ float As[2][RB * KT];   // 2 x 16 KB, swizzled content
    __shared__ float Bs[2][KT * HID];  // 2 x 4 KB, linear
    int t = threadIdx.x;
    int w = t >> 6, l = t & 63;
    int r0 = blockIdx.x * RB;
    int k0 = blockIdx.y * KCHUNK;
    int cg = t & 3;           // 4 col groups of 8
    int rp2 = (t >> 2) * 2;   // row pair base 0..126
    int e = (rp2 >> 1) & 7;   // swizzle key
    float4 acc00 = {0, 0, 0, 0}, acc01 = {0, 0, 0, 0};
    float4 acc10 = {0, 0, 0, 0}, acc11 = {0, 0, 0, 0};

    // A staging geometry: call i stages LDS float4 slots s=(w*4+i)*64+l
    // (wave-uniform LDS base, lane gives +l*16B). row=s>>3, p=s&7.
    int arow[4], afi[4];
#pragma unroll
    for (int i = 0; i < 4; ++i) {
        int s = ((w * 4 + i) << 6) + l;
        arow[i] = s >> 3;
        afi[i] = (s & 7) ^ ((arow[i] >> 1) & 7);
    }
    int bslot = (w << 6) + l;  // B float4 slot staged by this lane

    // prologue: stage tile 0 into buffer 0
#pragma unroll
    for (int i = 0; i < 4; ++i)
        gload16(&adj[(size_t)(r0 + arow[i]) * N + k0 + afi[i] * 4],
                &As[0][(w * 4 + i) << 8]);
    gload16(&Zs[(size_t)k0 * HID + bslot * 4], &Bs[0][w << 8]);
    __syncthreads();

    int cur = 0;
    for (int tile = 0; tile < NT; ++tile) {
        // issue next tile's loads first: they fly during this tile's compute
        if (tile + 1 < NT) {
            int ktn = k0 + (tile + 1) * KT;
            int nxt = cur ^ 1;
#pragma unroll
            for (int i = 0; i < 4; ++i)
                gload16(&adj[(size_t)(r0 + arow[i]) * N + ktn + afi[i] * 4],
                        &As[nxt][(w * 4 + i) << 8]);
            gload16(&Zs[(size_t)ktn * HID + bslot * 4], &Bs[nxt][w << 8]);
        }
        const float* A = As[cur];
        const float* B = Bs[cur];
#pragma unroll
        for (int kk = 0; kk < KT; kk += 4) {
            int s0 = ((kk >> 2) ^ e) * 4;
            float a0[4], a1[4];
            *(float4*)a0 = *(const float4*)&A[rp2 * KT + s0];
            *(float4*)a1 = *(const float4*)&A[(rp2 + 1) * KT + s0];
#pragma unroll
            for (int j = 0; j < 4; ++j) {
                float4 z0 = *(const float4*)&B[(kk + j) * HID + cg * 8];
                float4 z1 = *(const float4*)&B[(kk + j) * HID + cg * 8 + 4];
                fma4(acc00, a0[j], z0);
                fma4(acc01, a0[j], z1);
                fma4(acc10, a1[j], z0);
                fma4(acc11, a1[j], z1);
            }
        }
        __syncthreads();  // drains vmcnt(0): next buffer is ready; reads done
        cur ^= 1;
    }

    float* p0 = P + (size_t)blockIdx.y * (N * HID) + (size_t)(r0 + rp2) * HID + cg * 8;
    float* p1 = p0 + HID;
    *(float4*)(p0)     = acc00;
    *(float4*)(p0 + 4) = acc01;
    *(float4*)(p1)     = acc10;
    *(float4*)(p1 + 4) = acc11;
}

// H = relu(dinv * (sum_sk P[sk] + Zs)); then Zout = dinv * (H @ W2 + b2)
__global__ __launch_bounds__(256) void k_fin_z2(const float* __restrict__ P,
                                                const float* __restrict__ Zin,
                                                const float* __restrict__ dinv,
                                                const float* __restrict__ W2,
                                                const float* __restrict__ b2,
                                                float* __restrict__ Zout) {
    __shared__ float Ws[HID * HID];  // 1024 floats
    __shared__ float hs[8][HID];
    int t = threadIdx.x;
    int row0 = blockIdx.x * 8;
    *(float4*)&Ws[t * 4] = *(const float4*)&W2[t * 4];
    int r = t >> 5, c = t & 31;
    size_t idx = (size_t)row0 * HID + t;
    float v = Zin[idx];
#pragma unroll
    for (int s = 0; s < SK; ++s) v += P[(size_t)s * (N * HID) + idx];
    int row = row0 + r;
    hs[r][c] = fmaxf(dinv[row] * v, 0.f);
    __syncthreads();
    float acc = b2[c];
#pragma unroll
    for (int k = 0; k < HID; ++k) acc = fmaf(hs[r][k], Ws[k * HID + c], acc);
    Zout[idx] = dinv[row] * acc;
}

// H = relu(dinv * (sum_sk P[sk] + Zs)); out[i] = H[i] @ W3 + b3
__global__ __launch_bounds__(256) void k_fin_out(const float* __restrict__ P,
                                                 const float* __restrict__ Zin,
                                                 const float* __restrict__ dinv,
                                                 const float* __restrict__ W3,
                                                 const float* __restrict__ b3,
                                                 float* __restrict__ out) {
    int t = threadIdx.x;
    size_t idx = (size_t)blockIdx.x * 256 + t;
    int row = (int)(idx >> 5);
    int c = t & 31;
    float v = Zin[idx];
#pragma unroll
    for (int s = 0; s < SK; ++s) v += P[(size_t)s * (N * HID) + idx];
    float h = fmaxf(dinv[row] * v, 0.f);
    float hw = h * W3[c];
#pragma unroll
    for (int off = 16; off > 0; off >>= 1) hw += __shfl_xor(hw, off, 32);
    if (c == 0) out[row] = hw + b3[0];
}

extern "C" void kernel_launch(void* const* d_in, const int* in_sizes, int n_in,
                              void* d_out, int out_size, void* d_ws, size_t ws_size,
                              hipStream_t stream) {
    const float* x   = (const float*)d_in[0];
    const float* adj = (const float*)d_in[1];
    const float* W1  = (const float*)d_in[2];
    const float* b1  = (const float*)d_in[3];
    const float* W2  = (const float*)d_in[4];
    const float* b2  = (const float*)d_in[5];
    const float* W3  = (const float*)d_in[6];
    const float* b3  = (const float*)d_in[7];
    float* out = (float*)d_out;

    float* dinv = (float*)d_ws;               // N floats
    float* Zs1  = dinv + N;                   // N*32 floats (1 MB)
    float* Zs2  = Zs1 + (size_t)N * HID;      // N*32 floats (1 MB)
    float* P    = Zs2 + (size_t)N * HID;      // SK*N*32 floats (16 MB)

    k_deg_z1<<<N / 8, 256, 0, stream>>>(adj, x, W1, b1, dinv, Zs1);

    k_spmm<<<dim3(N / RB, SK), 256, 0, stream>>>(adj, Zs1, P);
    k_fin_z2<<<N / 8, 256, 0, stream>>>(P, Zs1, dinv, W2, b2, Zs2);

    k_spmm<<<dim3(N / RB, SK), 256, 0, stream>>>(adj, Zs2, P);
    k_fin_out<<<N * HID / 256, 256, 0, stream>>>(P, Zs2, dinv, W3, b3, out);
}